// Round 13
// baseline (133.405 us; speedup 1.0000x reference)
//
#include <hip/hip_runtime.h>
#include <math.h>

typedef _Float16 h4 __attribute__((ext_vector_type(4)));
typedef _Float16 h2 __attribute__((ext_vector_type(2)));
typedef float    f4 __attribute__((ext_vector_type(4)));

namespace {
constexpr float LB = 4.5f;                       // HSGP half-domain
constexpr float WF = (float)M_PI / (2.0f * LB);  // base frequency (rad)
constexpr float REV = 1.0f / (4.0f * LB);        // WF/(2*pi): radians->revolutions
}

// ---------------------------------------------------------------------------
// Setup: 7 shared A-fragments for v_mfma_f32_16x16x16_f16.
//   d2=0..2: A_d[a][j]  = beta[d,a*12+j]*sqrt(S(a,j))/LB       (u = A*sin)
//   d2=3..5: A'_d[a][j] = A_d[a][j] * W*(j+1)                  (w = A'*cos)
//   d2=6   : selector A_sel[r][k] = (k%4 == r%4) ? 1 : 0       (cross-group sum)
// Fragment layout: lane l holds A[l&15][4*(l>>4)+t], t=0..3.
// ---------------------------------------------------------------------------
__global__ void setup_A_kernel(const float* __restrict__ beta,
                               const float* __restrict__ ls,
                               const float* __restrict__ alpha,
                               _Float16* __restrict__ A) {
    int idx = blockIdx.x * blockDim.x + threadIdx.x;
    if (idx >= 1792) return;
    int d2 = idx >> 8;              // 0..6
    int l = (idx >> 2) & 63;
    int t = idx & 3;
    int r = l & 15;                 // output row
    int k = ((l >> 4) << 2) + t;    // K index
    float val = 0.0f;
    if (d2 == 6) {
        val = ((k & 3) == (r & 3)) ? 1.0f : 0.0f;
    } else if (r < 12 && k < 12) {
        int d = (d2 >= 3) ? d2 - 3 : d2;
        float w0 = WF * (float)(r + 1);
        float w1 = WF * (float)(k + 1);
        float l0 = ls[0], l1 = ls[1], al = alpha[0];
        float S = al * al * (2.0f * (float)M_PI) * l0 * l1 *
                  expf(-0.5f * (l0 * l0 * w0 * w0 + l1 * l1 * w1 * w1));
        val = beta[d * 144 + r * 12 + k] * sqrtf(S) * (1.0f / LB);
        if (d2 >= 3) val *= WF * (float)(k + 1);   // bake j-frequency weight
    }
    A[idx] = (_Float16)val;
}

// ---------------------------------------------------------------------------
// 4 consecutive multiples mb..mb+3 of angle (2*pi*thr): HW trig in revolutions
// + angle-addition recurrence.
// ---------------------------------------------------------------------------
__device__ __forceinline__ void trig4r(float thr, float mb, float* s, float* c) {
    float s1 = __builtin_amdgcn_sinf(thr);
    float c1 = __builtin_amdgcn_cosf(thr);
    float mbr = mb * thr;
    s[0] = __builtin_amdgcn_sinf(mbr);
    c[0] = __builtin_amdgcn_cosf(mbr);
    #pragma unroll
    for (int t = 1; t < 4; ++t) {
        s[t] = fmaf(s[t - 1], c1,  c[t - 1] * s1);
        c[t] = fmaf(c[t - 1], c1, -(s[t - 1] * s1));
    }
}

__device__ __forceinline__ h4 pack4(float a, float b, float c, float d) {
    h2 lo = __builtin_bit_cast(h2, __builtin_amdgcn_cvt_pkrtz(a, b));
    h2 hi = __builtin_bit_cast(h2, __builtin_amdgcn_cvt_pkrtz(c, d));
    return __builtin_shufflevector(lo, hi, 0, 1, 2, 3);
}

// ---------------------------------------------------------------------------
// Main: one wave = TWO independent 16-element sets (ILP x2 to cover the
// serial dep chain trig->MFMA1->fold->MFMA2->Christoffel->AB: with one chain,
// 3 co-resident waves leave ~2.5x gap between the 49us issue floor and
// measured 123us). Element = lane&15, lane-group g = lane>>4 owns a-rows
// 4g..4g+3; selector-MFMA reduction (R12, verified).
// ---------------------------------------------------------------------------
__global__ __launch_bounds__(64)
void geo_kernel(const float* __restrict__ xg, const float* __restrict__ vg,
                const _Float16* Ag /* non-restrict-ish: pinned below */,
                float* __restrict__ out, int B)
{
    int lane = threadIdx.x;
    int g = lane >> 4;
    int eb0 = blockIdx.x << 5;
    if (eb0 >= B) return;
    int ebv[2] = { eb0, eb0 + 16 };
    if (ebv[1] + 16 > B) ebv[1] = B - 16;   // clamp: duplicates set A (benign)

    // ---- shared A fragments (14 VGPRs) ----
    union U8 { uint2 u; h4 h; };
    const uint2* Au = reinterpret_cast<const uint2*>(Ag);
    U8 a0, a1, a2, a3, a4, a5, a6;
    a0.u = Au[0 * 64 + lane];
    a1.u = Au[1 * 64 + lane];
    a2.u = Au[2 * 64 + lane];
    a3.u = Au[3 * 64 + lane];
    a4.u = Au[4 * 64 + lane];
    a5.u = Au[5 * 64 + lane];
    a6.u = Au[6 * 64 + lane];
    asm volatile("" ::: "memory");  // forbid reload of Ag inside the loop
    h4 A0 = a0.h, A1 = a1.h, A2 = a2.h;
    h4 A3 = a3.h, A4 = a4.h, A5 = a5.h;
    h4 SEL = a6.h;

    float mb = (float)(4 * g + 1);
    float Wm[4];
    #pragma unroll
    for (int t = 0; t < 4; ++t) Wm[t] = WF * (mb + (float)t);

    // ---- per-set state ----
    float X0[2], X1[2], V0[2], V1[2];
    float H1x[2], H2x[2], H3x[2], H1y[2], H2y[2], H3y[2];
    float G1x[2], G2x[2], G3x[2], G1y[2], G2y[2], G3y[2];
    unsigned off[2];
    const unsigned stride = 16u * (unsigned)B;   // bytes per time slot
    char* outc = reinterpret_cast<char*>(out);

    #pragma unroll
    for (int s = 0; s < 2; ++s) {
        int e = ebv[s] + (lane & 15);
        float2 xv = reinterpret_cast<const float2*>(xg)[e];
        float2 vv = reinterpret_cast<const float2*>(vg)[e];
        X0[s] = xv.x; X1[s] = xv.y; V0[s] = vv.x; V1[s] = vv.y;
        off[s] = 4u * ((((unsigned)(g >> 1) * (unsigned)B) + (unsigned)e) * 2u
                       + (unsigned)(g & 1));
        float sval = (g & 2) ? ((g & 1) ? V1[s] : V0[s]) : ((g & 1) ? X1[s] : X0[s]);
        *reinterpret_cast<float*>(outc + off[s]) = sval;
        H1x[s] = H2x[s] = H3x[s] = H1y[s] = H2y[s] = H3y[s] = 0.f;
        G1x[s] = G2x[s] = G3x[s] = G1y[s] = G2y[s] = G3y[s] = 0.f;
    }

    const float h = 1.0f / 99.0f;

    auto STEP = [&](int s, float hc0, float hc1, float hc2, float hc3) {
        float x0 = X0[s], x1 = X1[s], v0 = V0[s], v1 = V1[s];

        // ---- per-lane trig (revolutions): multiples 4g+1..4g+4, both dims ----
        float s0v[4], c0v[4], s1v[4], c1v[4], wc0[4];
        trig4r(fmaf(x0, REV, 0.25f), mb, s0v, c0v);
        trig4r(fmaf(x1, REV, 0.25f), mb, s1v, c1v);
        #pragma unroll
        for (int t = 0; t < 4; ++t) wc0[t] = Wm[t] * c0v[t];

        h4 bs = pack4(s1v[0], s1v[1], s1v[2], s1v[3]);
        h4 bc = pack4(c1v[0], c1v[1], c1v[2], c1v[3]);   // weights baked in A3..A5

        // ---- stage 1: u_d = A_d*sin1, w_d = A'_d*cos1 ----
        f4 z = {0.f, 0.f, 0.f, 0.f};
        f4 u0 = __builtin_amdgcn_mfma_f32_16x16x16f16(A0, bs, z, 0, 0, 0);
        f4 u1 = __builtin_amdgcn_mfma_f32_16x16x16f16(A1, bs, z, 0, 0, 0);
        f4 u2 = __builtin_amdgcn_mfma_f32_16x16x16f16(A2, bs, z, 0, 0, 0);
        f4 w0 = __builtin_amdgcn_mfma_f32_16x16x16f16(A3, bc, z, 0, 0, 0);
        f4 w1 = __builtin_amdgcn_mfma_f32_16x16x16f16(A4, bc, z, 0, 0, 0);
        f4 w2 = __builtin_amdgcn_mfma_f32_16x16x16f16(A5, bc, z, 0, 0, 0);

        // ---- per-lane fold over this lane's 4 a-rows ----
        float f0 = 0.f, f1 = 0.f, f2 = 0.f;
        float dA0 = 0.f, dA1 = 0.f, dA2 = 0.f;
        float dB0 = 0.f, dB1 = 0.f, dB2 = 0.f;
        #pragma unroll
        for (int t = 0; t < 4; ++t) {
            float sA = s0v[t], cA = wc0[t];
            f0  = fmaf(sA, u0[t], f0);   dA0 = fmaf(cA, u0[t], dA0);
            f1  = fmaf(sA, u1[t], f1);   dA1 = fmaf(cA, u1[t], dA1);
            f2  = fmaf(sA, u2[t], f2);   dA2 = fmaf(cA, u2[t], dA2);
            dB0 = fmaf(sA, w0[t], dB0);
            dB1 = fmaf(sA, w1[t], dB1);
            dB2 = fmaf(sA, w2[t], dB2);
        }

        // ---- fold vv (element-uniform across lane-groups) pre-reduction ----
        float vv00 = v0 * v0, vv11 = v1 * v1;
        float w01 = 2.0f * v0 * v1;
        float q0p = fmaf(dA0, vv00, fmaf(dB0, w01, fmaf(2.0f, dB1, -dA2) * vv11));
        float q1p = fmaf(fmaf(2.0f, dA1, -dB0), vv00, fmaf(dA2, w01, dB2 * vv11));

        // ---- stage 2: selector-MFMA cross-group reduction (no shuffles) ----
        h4 r1 = pack4(f0, f1, f2, q0p);
        h4 r2 = pack4(q1p, 0.0f, 0.0f, 0.0f);
        f4 D1 = __builtin_amdgcn_mfma_f32_16x16x16f16(SEL, r1, z, 0, 0, 0);
        f4 D2 = __builtin_amdgcn_mfma_f32_16x16x16f16(SEL, r2, z, 0, 0, 0);
        float F0 = D1[0], F1 = D1[1], F2 = D1[2], Q0 = D1[3], Q1 = D2[0];

        // ---- 2x2 Christoffel acceleration (lockstep on all lanes) ----
        float G00 = F0 + 1.0f, G01 = F1, G11 = F2 + 1.0f;
        float det = fmaf(G00, G11, -(G01 * G01));
        float rdet = __builtin_amdgcn_rcpf(det);
        float a0v = -0.5f * rdet * fmaf(G11, Q0, -(G01 * Q1));
        float a1v = -0.5f * rdet * fmaf(G00, Q1, -(G01 * Q0));

        // ---- Adams-Bashforth update, h baked into coeffs ----
        x0 = fmaf(hc0, v0, fmaf(hc1, H1x[s], fmaf(hc2, H2x[s], fmaf(hc3, H3x[s], x0))));
        x1 = fmaf(hc0, v1, fmaf(hc1, H1y[s], fmaf(hc2, H2y[s], fmaf(hc3, H3y[s], x1))));
        float nv0 = fmaf(hc0, a0v, fmaf(hc1, G1x[s], fmaf(hc2, G2x[s], fmaf(hc3, G3x[s], v0))));
        float nv1 = fmaf(hc0, a1v, fmaf(hc1, G1y[s], fmaf(hc2, G2y[s], fmaf(hc3, G3y[s], v1))));
        H3x[s] = H2x[s]; H2x[s] = H1x[s]; H1x[s] = v0;
        H3y[s] = H2y[s]; H2y[s] = H1y[s]; H1y[s] = v1;
        G3x[s] = G2x[s]; G2x[s] = G1x[s]; G1x[s] = a0v;
        G3y[s] = G2y[s]; G2y[s] = G1y[s]; G1y[s] = a1v;
        X0[s] = x0; X1[s] = x1; V0[s] = nv0; V1[s] = nv1;

        off[s] += stride;
        float sval = (g & 2) ? ((g & 1) ? nv1 : nv0) : ((g & 1) ? x1 : x0);
        *reinterpret_cast<float*>(outc + off[s]) = sval;
    };

    // startup (orders 1..3), then steady AB4
    STEP(0, h * 1.0f, 0.0f, 0.0f, 0.0f);
    STEP(1, h * 1.0f, 0.0f, 0.0f, 0.0f);
    STEP(0, h * 1.5f, h * -0.5f, 0.0f, 0.0f);
    STEP(1, h * 1.5f, h * -0.5f, 0.0f, 0.0f);
    STEP(0, h * 23.0f / 12.0f, h * -16.0f / 12.0f, h * 5.0f / 12.0f, 0.0f);
    STEP(1, h * 23.0f / 12.0f, h * -16.0f / 12.0f, h * 5.0f / 12.0f, 0.0f);
    #pragma unroll 2
    for (int t = 3; t < 99; ++t) {
        STEP(0, h * 55.0f / 24.0f, h * -59.0f / 24.0f, h * 37.0f / 24.0f, h * -9.0f / 24.0f);
        STEP(1, h * 55.0f / 24.0f, h * -59.0f / 24.0f, h * 37.0f / 24.0f, h * -9.0f / 24.0f);
    }
}

// ---------------------------------------------------------------------------
extern "C" void kernel_launch(void* const* d_in, const int* in_sizes, int n_in,
                              void* d_out, int out_size, void* d_ws, size_t ws_size,
                              hipStream_t stream) {
    const float* x0    = (const float*)d_in[0];
    const float* v0    = (const float*)d_in[1];
    const float* beta  = (const float*)d_in[2];
    const float* ls    = (const float*)d_in[3];
    const float* alpha = (const float*)d_in[4];
    float* out = (float*)d_out;
    _Float16* A = (_Float16*)d_ws;   // 1792 halfs: 7 MFMA A-fragments

    int B = in_sizes[0] / 2;         // 50000

    hipLaunchKernelGGL(setup_A_kernel, dim3(28), dim3(64), 0, stream,
                       beta, ls, alpha, A);

    int grid = (B + 31) / 32;        // 1563 blocks: 1 wave = 2 element-sets
    hipLaunchKernelGGL(geo_kernel, dim3(grid), dim3(64), 0, stream,
                       x0, v0, A, out, B);
}

// Round 14
// 116.087 us; speedup vs baseline: 1.1492x; 1.1492x over previous
//
#include <hip/hip_runtime.h>
#include <math.h>

typedef _Float16 h4 __attribute__((ext_vector_type(4)));
typedef _Float16 h2 __attribute__((ext_vector_type(2)));
typedef float    f4 __attribute__((ext_vector_type(4)));

namespace {
constexpr float LB = 4.5f;                       // HSGP half-domain
constexpr float WF = (float)M_PI / (2.0f * LB);  // base frequency (rad)
constexpr float REV = 1.0f / (4.0f * LB);        // WF/(2*pi): radians->revolutions
}

// ---------------------------------------------------------------------------
// Setup: 7 shared A-fragments for v_mfma_f32_16x16x16_f16.
//   d2=0..2: A_d[a][j]  = beta[d,a*12+j]*sqrt(S(a,j))/LB       (u = A*sin)
//   d2=3..5: A'_d[a][j] = A_d[a][j] * W*(j+1)                  (w = A'*cos)
//   d2=6   : selector A_sel[r][k] = (k%4 == r%4) ? 1 : 0       (cross-group sum)
// Fragment layout: lane l holds A[l&15][4*(l>>4)+t], t=0..3.
// ---------------------------------------------------------------------------
__global__ void setup_A_kernel(const float* __restrict__ beta,
                               const float* __restrict__ ls,
                               const float* __restrict__ alpha,
                               _Float16* __restrict__ A) {
    int idx = blockIdx.x * blockDim.x + threadIdx.x;
    if (idx >= 1792) return;
    int d2 = idx >> 8;              // 0..6
    int l = (idx >> 2) & 63;
    int t = idx & 3;
    int r = l & 15;                 // output row
    int k = ((l >> 4) << 2) + t;    // K index
    float val = 0.0f;
    if (d2 == 6) {
        val = ((k & 3) == (r & 3)) ? 1.0f : 0.0f;
    } else if (r < 12 && k < 12) {
        int d = (d2 >= 3) ? d2 - 3 : d2;
        float w0 = WF * (float)(r + 1);
        float w1 = WF * (float)(k + 1);
        float l0 = ls[0], l1 = ls[1], al = alpha[0];
        float S = al * al * (2.0f * (float)M_PI) * l0 * l1 *
                  expf(-0.5f * (l0 * l0 * w0 * w0 + l1 * l1 * w1 * w1));
        val = beta[d * 144 + r * 12 + k] * sqrtf(S) * (1.0f / LB);
        if (d2 >= 3) val *= WF * (float)(k + 1);   // bake j-frequency weight
    }
    A[idx] = (_Float16)val;
}

// ---------------------------------------------------------------------------
// 4 consecutive multiples mb..mb+3 of angle (2*pi*thr): HW trig in revolutions
// + angle-addition recurrence.
// ---------------------------------------------------------------------------
__device__ __forceinline__ void trig4r(float thr, float mb, float* s, float* c) {
    float s1 = __builtin_amdgcn_sinf(thr);
    float c1 = __builtin_amdgcn_cosf(thr);
    float mbr = mb * thr;
    s[0] = __builtin_amdgcn_sinf(mbr);
    c[0] = __builtin_amdgcn_cosf(mbr);
    #pragma unroll
    for (int t = 1; t < 4; ++t) {
        s[t] = fmaf(s[t - 1], c1,  c[t - 1] * s1);
        c[t] = fmaf(c[t - 1], c1, -(s[t - 1] * s1));
    }
}

__device__ __forceinline__ h4 pack4(float a, float b, float c, float d) {
    h2 lo = __builtin_bit_cast(h2, __builtin_amdgcn_cvt_pkrtz(a, b));
    h2 hi = __builtin_bit_cast(h2, __builtin_amdgcn_cvt_pkrtz(c, d));
    return __builtin_shufflevector(lo, hi, 0, 1, 2, 3);
}

// ---------------------------------------------------------------------------
// Main: one wave = 16 elements; element = lane&15, lane-group g = lane>>4
// owns a-rows 4g..4g+3. SOFTWARE-PIPELINED: the Adams x-update needs only the
// v-history, so x(t+1) is known at the START of step t; the heavy front-end
// (trig + 6 stage-1 MFMAs + 36-FMA fold -> 9 partials, x-only) for step t+1
// is issued alongside the short back-end chain of step t (vv-fold -> selector
// MFMA2 -> Christoffel -> v-update). Cross-iteration critical path drops
// ~250 -> ~100 cyc; front-end fills the stall shadow. Arithmetic identical
// to R12 (123 us), just reordered.
// ---------------------------------------------------------------------------
__global__ __launch_bounds__(64)
void geo_kernel(const float* __restrict__ xg, const float* __restrict__ vg,
                const _Float16* Ag /* non-restrict-ish: pinned below */,
                float* __restrict__ out, int B)
{
    int lane = threadIdx.x;
    int ebase = blockIdx.x << 4;
    if (ebase >= B) return;
    int g = lane >> 4;
    int e = ebase + (lane & 15);
    if (e >= B) e = B - 1;          // benign clamp (duplicate writes identical)

    // ---- shared A fragments (14 VGPRs) ----
    union U8 { uint2 u; h4 h; };
    const uint2* Au = reinterpret_cast<const uint2*>(Ag);
    U8 a0, a1, a2, a3, a4, a5, a6;
    a0.u = Au[0 * 64 + lane];
    a1.u = Au[1 * 64 + lane];
    a2.u = Au[2 * 64 + lane];
    a3.u = Au[3 * 64 + lane];
    a4.u = Au[4 * 64 + lane];
    a5.u = Au[5 * 64 + lane];
    a6.u = Au[6 * 64 + lane];
    asm volatile("" ::: "memory");  // forbid reload of Ag inside the loop
    h4 A0 = a0.h, A1 = a1.h, A2 = a2.h;
    h4 A3 = a3.h, A4 = a4.h, A5 = a5.h;
    h4 SEL = a6.h;

    float mb = (float)(4 * g + 1);
    float Wm[4];
    #pragma unroll
    for (int t = 0; t < 4; ++t) Wm[t] = WF * (mb + (float)t);

    float2 xv = reinterpret_cast<const float2*>(xg)[e];
    float2 vv2 = reinterpret_cast<const float2*>(vg)[e];
    float x0 = xv.x, x1 = xv.y, v0 = vv2.x, v1 = vv2.y;

    // per-lane output slot: out[t][g>>1][e][g&1]
    unsigned off = 4u * ((((unsigned)(g >> 1) * (unsigned)B) + (unsigned)e) * 2u
                         + (unsigned)(g & 1));
    const unsigned stride = 16u * (unsigned)B;   // bytes per time slot
    char* outc = reinterpret_cast<char*>(out);
    {
        float sval = (g & 2) ? ((g & 1) ? v1 : v0) : ((g & 1) ? x1 : x0);
        *reinterpret_cast<float*>(outc + off) = sval;
    }

    // Adams histories (older entries)
    float h1x = 0.f, h2x = 0.f, h3x = 0.f, h1y = 0.f, h2y = 0.f, h3y = 0.f;
    float g1x = 0.f, g2x = 0.f, g3x = 0.f, g1y = 0.f, g2y = 0.f, g3y = 0.f;
    const float h = 1.0f / 99.0f;

    // front-end partials for the CURRENT step (computed from x(t) only)
    float pf0, pf1, pf2, pA0, pA1, pA2, pB0, pB1, pB2;

    auto FRONT = [&](float xa, float xb,
                     float& f0, float& f1, float& f2,
                     float& dA0, float& dA1, float& dA2,
                     float& dB0, float& dB1, float& dB2) {
        float s0v[4], c0v[4], s1v[4], c1v[4], wc0[4];
        trig4r(fmaf(xa, REV, 0.25f), mb, s0v, c0v);
        trig4r(fmaf(xb, REV, 0.25f), mb, s1v, c1v);
        #pragma unroll
        for (int t = 0; t < 4; ++t) wc0[t] = Wm[t] * c0v[t];

        h4 bs = pack4(s1v[0], s1v[1], s1v[2], s1v[3]);
        h4 bc = pack4(c1v[0], c1v[1], c1v[2], c1v[3]);   // weights baked in A3..A5

        f4 z = {0.f, 0.f, 0.f, 0.f};
        f4 u0 = __builtin_amdgcn_mfma_f32_16x16x16f16(A0, bs, z, 0, 0, 0);
        f4 u1 = __builtin_amdgcn_mfma_f32_16x16x16f16(A1, bs, z, 0, 0, 0);
        f4 u2 = __builtin_amdgcn_mfma_f32_16x16x16f16(A2, bs, z, 0, 0, 0);
        f4 w0 = __builtin_amdgcn_mfma_f32_16x16x16f16(A3, bc, z, 0, 0, 0);
        f4 w1 = __builtin_amdgcn_mfma_f32_16x16x16f16(A4, bc, z, 0, 0, 0);
        f4 w2 = __builtin_amdgcn_mfma_f32_16x16x16f16(A5, bc, z, 0, 0, 0);

        f0 = 0.f; f1 = 0.f; f2 = 0.f;
        dA0 = 0.f; dA1 = 0.f; dA2 = 0.f;
        dB0 = 0.f; dB1 = 0.f; dB2 = 0.f;
        #pragma unroll
        for (int t = 0; t < 4; ++t) {
            float sA = s0v[t], cA = wc0[t];
            f0  = fmaf(sA, u0[t], f0);   dA0 = fmaf(cA, u0[t], dA0);
            f1  = fmaf(sA, u1[t], f1);   dA1 = fmaf(cA, u1[t], dA1);
            f2  = fmaf(sA, u2[t], f2);   dA2 = fmaf(cA, u2[t], dA2);
            dB0 = fmaf(sA, w0[t], dB0);
            dB1 = fmaf(sA, w1[t], dB1);
            dB2 = fmaf(sA, w2[t], dB2);
        }
    };

    // prime the pipeline with step-0 partials
    FRONT(x0, x1, pf0, pf1, pf2, pA0, pA1, pA2, pB0, pB1, pB2);

    auto STEP = [&](float hc0, float hc1, float hc2, float hc3, bool front) {
        // ---- x(t+1): needs only v-history (the pipelining enabler) ----
        float nx0 = fmaf(hc0, v0, fmaf(hc1, h1x, fmaf(hc2, h2x, fmaf(hc3, h3x, x0))));
        float nx1 = fmaf(hc0, v1, fmaf(hc1, h1y, fmaf(hc2, h2y, fmaf(hc3, h3y, x1))));
        h3x = h2x; h2x = h1x; h1x = v0;
        h3y = h2y; h2y = h1y; h1y = v1;

        // ---- issue next step's front-end (independent of v(t+1)) ----
        float nf0, nf1, nf2, nA0, nA1, nA2, nB0, nB1, nB2;
        if (front)
            FRONT(nx0, nx1, nf0, nf1, nf2, nA0, nA1, nA2, nB0, nB1, nB2);

        // ---- back-end of step t: the only serial chain ----
        float vv00 = v0 * v0, vv11 = v1 * v1;
        float w01 = 2.0f * v0 * v1;
        float q0p = fmaf(pA0, vv00, fmaf(pB0, w01, fmaf(2.0f, pB1, -pA2) * vv11));
        float q1p = fmaf(fmaf(2.0f, pA1, -pB0), vv00, fmaf(pA2, w01, pB2 * vv11));

        h4 r1 = pack4(pf0, pf1, pf2, q0p);
        h4 r2 = pack4(q1p, 0.0f, 0.0f, 0.0f);
        f4 z = {0.f, 0.f, 0.f, 0.f};
        f4 D1 = __builtin_amdgcn_mfma_f32_16x16x16f16(SEL, r1, z, 0, 0, 0);
        f4 D2 = __builtin_amdgcn_mfma_f32_16x16x16f16(SEL, r2, z, 0, 0, 0);
        float F0 = D1[0], F1 = D1[1], F2 = D1[2], Q0 = D1[3], Q1 = D2[0];

        float G00 = F0 + 1.0f, G01 = F1, G11 = F2 + 1.0f;
        float det = fmaf(G00, G11, -(G01 * G01));
        float rdet = __builtin_amdgcn_rcpf(det);
        float a0v = -0.5f * rdet * fmaf(G11, Q0, -(G01 * Q1));
        float a1v = -0.5f * rdet * fmaf(G00, Q1, -(G01 * Q0));

        float nv0 = fmaf(hc0, a0v, fmaf(hc1, g1x, fmaf(hc2, g2x, fmaf(hc3, g3x, v0))));
        float nv1 = fmaf(hc0, a1v, fmaf(hc1, g1y, fmaf(hc2, g2y, fmaf(hc3, g3y, v1))));
        g3x = g2x; g2x = g1x; g1x = a0v;
        g3y = g2y; g2y = g1y; g1y = a1v;

        x0 = nx0; x1 = nx1; v0 = nv0; v1 = nv1;
        if (front) {
            pf0 = nf0; pf1 = nf1; pf2 = nf2;
            pA0 = nA0; pA1 = nA1; pA2 = nA2;
            pB0 = nB0; pB1 = nB1; pB2 = nB2;
        }

        off += stride;
        float sval = (g & 2) ? ((g & 1) ? v1 : v0) : ((g & 1) ? x1 : x0);
        *reinterpret_cast<float*>(outc + off) = sval;
    };

    // startup (orders 1..3), steady AB4, final step without front-end
    STEP(h * 1.0f, 0.0f, 0.0f, 0.0f, true);
    STEP(h * 1.5f, h * -0.5f, 0.0f, 0.0f, true);
    STEP(h * 23.0f / 12.0f, h * -16.0f / 12.0f, h * 5.0f / 12.0f, 0.0f, true);
    #pragma unroll 2
    for (int t = 3; t < 98; ++t)
        STEP(h * 55.0f / 24.0f, h * -59.0f / 24.0f, h * 37.0f / 24.0f, h * -9.0f / 24.0f, true);
    STEP(h * 55.0f / 24.0f, h * -59.0f / 24.0f, h * 37.0f / 24.0f, h * -9.0f / 24.0f, false);
}

// ---------------------------------------------------------------------------
extern "C" void kernel_launch(void* const* d_in, const int* in_sizes, int n_in,
                              void* d_out, int out_size, void* d_ws, size_t ws_size,
                              hipStream_t stream) {
    const float* x0    = (const float*)d_in[0];
    const float* v0    = (const float*)d_in[1];
    const float* beta  = (const float*)d_in[2];
    const float* ls    = (const float*)d_in[3];
    const float* alpha = (const float*)d_in[4];
    float* out = (float*)d_out;
    _Float16* A = (_Float16*)d_ws;   // 1792 halfs: 7 MFMA A-fragments

    int B = in_sizes[0] / 2;         // 50000

    hipLaunchKernelGGL(setup_A_kernel, dim3(28), dim3(64), 0, stream,
                       beta, ls, alpha, A);

    int grid = (B + 15) / 16;        // 3125 single-wave blocks
    hipLaunchKernelGGL(geo_kernel, dim3(grid), dim3(64), 0, stream,
                       x0, v0, A, out, B);
}